// Round 6
// baseline (5514.494 us; speedup 1.0000x reference)
//
#include <hip/hip_runtime.h>

// ---------------- problem constants ----------------
#define BUFF  64
#define STK   48
#define HIST  96
#define NOUT  82

typedef __bf16 bf16;
typedef __attribute__((ext_vector_type(8))) __bf16 bf16x8;
typedef __attribute__((ext_vector_type(4))) float   f32x4;

__device__ __forceinline__ float sigf(float x)   { return 1.f / (1.f + __expf(-x)); }
__device__ __forceinline__ float tanhf_(float x) { return 1.f - 2.f / (1.f + __expf(2.f * x)); }

__device__ __forceinline__ unsigned pack2(const float* p) {
  union { unsigned u; bf16 h[2]; } r;
  r.h[0] = (bf16)p[0]; r.h[1] = (bf16)p[1];
  return r.u;
}

// =====================================================================
// Kernel 1: embedding MLP (unchanged, proven).
// =====================================================================
__global__ __launch_bounds__(256) void k_emb(
    const int* bw, const int* bp, const int* cw, const int* cp,
    const float* w_emb, const float* p_emb, const float* embW, const float* embB,
    bf16* comp_emb, bf16* buff_emb)
{
  __shared__ __align__(16) char sm[138752];
  bf16*  A  = (bf16*)sm;                    // [64][360]
  bf16*  Wt = (bf16*)(sm + 46080);          // [128][360]
  float* sb = (float*)(sm + 46080 + 92160); // [128]

  const int tid = threadIdx.x;
  const int r0  = blockIdx.x * 64;

  for (int i = tid; i < 64 * 176; i += 256) {
    int m = i / 176, c2 = i % 176, e0 = 2 * c2;
    int r = r0 + m;
    unsigned v;
    if (e0 < 300) {
      int word = (r < 98304) ? cw[r] : bw[r - 98304];
      v = pack2(w_emb + word * 300 + e0);
    } else if (e0 < 350) {
      int pos = (r < 98304) ? cp[r] : bp[r - 98304];
      v = pack2(p_emb + pos * 50 + (e0 - 300));
    } else v = 0u;
    *(unsigned*)(A + m * 360 + e0) = v;
  }
  for (int i = tid; i < 350 * 128; i += 256) {
    int k = i >> 7, n = i & 127;
    Wt[n * 360 + k] = (bf16)embW[i];
  }
  { int i = tid; if (i < 256) { int n = i >> 1; Wt[n * 360 + 350 + (i & 1)] = (bf16)0.f; } }
  if (tid < 128) sb[tid] = embB[tid];
  __syncthreads();

  const int wv = tid >> 6, lane = tid & 63, l15 = lane & 15, quad = lane >> 4;
  f32x4 acc[8];
#pragma unroll
  for (int i = 0; i < 8; ++i) acc[i] = (f32x4){0.f, 0.f, 0.f, 0.f};

  const bf16* Arow = A + (wv * 16 + l15) * 360;
  for (int ks = 0; ks < 11; ++ks) {
    int kq = ks * 32 + quad * 8;
    bf16x8 a = *(const bf16x8*)(Arow + kq);
#pragma unroll
    for (int nt = 0; nt < 8; ++nt) {
      bf16x8 b = *(const bf16x8*)(Wt + (nt * 16 + l15) * 360 + kq);
      acc[nt] = __builtin_amdgcn_mfma_f32_16x16x32_bf16(a, b, acc[nt], 0, 0, 0);
    }
  }
#pragma unroll
  for (int nt = 0; nt < 8; ++nt)
#pragma unroll
    for (int rr = 0; rr < 4; ++rr) {
      int row = wv * 16 + quad * 4 + rr;
      int n   = nt * 16 + l15;
      float z = fmaxf(acc[nt][rr] + sb[n], 0.f);
      int r = r0 + row;
      bf16 o = (bf16)z;
      if (r < 98304) comp_emb[r * 128 + n] = o;
      else           buff_emb[(r - 98304) * 128 + n] = o;
    }
}

// =====================================================================
// Kernel 2: compose (unchanged, proven).
// =====================================================================
__global__ __launch_bounds__(256) void k_compose(
    const int* cw, const int* caid, const int* calen,
    const bf16* comp_emb, const float* ca_emb, const float* recW, const float* recB,
    bf16* stack_emb)
{
  __shared__ __align__(16) char sm[129344];
  bf16*  Wt   = (bf16*)sm;              // [128][328]
  bf16*  X    = (bf16*)(sm + 83968);    // [16][328]
  bf16*  VALS = (bf16*)(sm + 94464);    // [16][8][128]
  float* recb = (float*)(sm + 127232);  // [128]
  int*   IH   = (int*)(sm + 127744);
  int*   ID   = (int*)(sm + 128256);
  int*   AN   = (int*)(sm + 128768);
  int*   ALEN = (int*)(sm + 129280);

  const int tid = threadIdx.x;
  const int bs0 = blockIdx.x * 16;

  for (int i = tid; i < 306 * 128; i += 256) {
    int k = i >> 7, n = i & 127;
    Wt[n * 328 + k] = (bf16)recW[i];
  }
  for (int i = tid; i < 128 * 22; i += 256) {
    int n = i / 22, k = 306 + i % 22;
    Wt[n * 328 + k] = (bf16)0.f;
  }
  if (tid < 128) recb[tid] = recB[tid];
  if (tid < 16) {
    int bs = bs0 + tid;
    int hid[8], did[8];
#pragma unroll
    for (int m = 0; m < 8; ++m) { hid[m] = cw[bs * 16 + 2 * m]; did[m] = cw[bs * 16 + 2 * m + 1]; }
    for (int n = 0; n < 8; ++n) {
      int ih = -1, idd = -1;
      for (int m = 0; m < n; ++m) { if (hid[m] == hid[n]) ih = m; if (hid[m] == did[n]) idd = m; }
      IH[tid * 8 + n] = ih; ID[tid * 8 + n] = idd; AN[tid * 8 + n] = caid[bs * 8 + n];
    }
    ALEN[tid] = calen[bs];
  }
  __syncthreads();

  const int wv = tid >> 6, lane = tid & 63, l15 = lane & 15, quad = lane >> 4;

  for (int n = 0; n < 8; ++n) {
    for (int i = tid; i < 16 * 160; i += 256) {
      int p = i / 160, c2 = i % 160, e0 = 2 * c2;
      int bs = bs0 + p;
      unsigned v;
      if (e0 < 128) {
        int ih = IH[p * 8 + n];
        v = (ih >= 0) ? *(const unsigned*)(VALS + (p * 8 + ih) * 128 + e0)
                      : *(const unsigned*)(comp_emb + (bs * 16 + 2 * n) * 128 + e0);
      } else if (e0 < 178) {
        v = pack2(ca_emb + AN[p * 8 + n] * 50 + (e0 - 128));
      } else if (e0 < 306) {
        int e = e0 - 178;
        int idd = ID[p * 8 + n];
        v = (idd >= 0) ? *(const unsigned*)(VALS + (p * 8 + idd) * 128 + e)
                       : *(const unsigned*)(comp_emb + (bs * 16 + 2 * n + 1) * 128 + e);
      } else v = 0u;
      *(unsigned*)(X + p * 328 + e0) = v;
    }
    __syncthreads();

    f32x4 acc[2];
    acc[0] = (f32x4){0.f,0.f,0.f,0.f}; acc[1] = (f32x4){0.f,0.f,0.f,0.f};
    for (int ks = 0; ks < 10; ++ks) {
      int kq = ks * 32 + quad * 8;
      bf16x8 a = *(const bf16x8*)(X + l15 * 328 + kq);
#pragma unroll
      for (int t2 = 0; t2 < 2; ++t2) {
        int nt = 2 * wv + t2;
        bf16x8 b = *(const bf16x8*)(Wt + (nt * 16 + l15) * 328 + kq);
        acc[t2] = __builtin_amdgcn_mfma_f32_16x16x32_bf16(a, b, acc[t2], 0, 0, 0);
      }
    }
    __syncthreads();
#pragma unroll
    for (int t2 = 0; t2 < 2; ++t2) {
      int nt = 2 * wv + t2;
#pragma unroll
      for (int rr = 0; rr < 4; ++rr) {
        int p = quad * 4 + rr;
        int col = nt * 16 + l15;
        VALS[(p * 8 + n) * 128 + col] = (bf16)tanhf_(acc[t2][rr] + recb[col]);
      }
    }
    __syncthreads();
  }

  for (int i = tid; i < 16 * 64; i += 256) {
    int p = i / 64, c2 = i % 64, e0 = 2 * c2;
    int bs = bs0 + p;
    int al = ALEN[p];
    unsigned v = (al == 0) ? *(const unsigned*)(comp_emb + (bs * 16) * 128 + e0)
                           : *(const unsigned*)(VALS + (p * 8 + (al - 1)) * 128 + e0);
    *(unsigned*)(stack_emb + bs * 128 + e0) = v;
  }
}

// =====================================================================
// Kernel 2.5: weight prep — fp32 W[K][1024] -> bf16 W^T[1024][Kd].
// a0 (m==2): src K=306 remapped to Kd=320 (x 50->64 zero-padded).
// Runs AFTER k_compose; W^T aliases the then-dead comp_emb workspace.
// =====================================================================
__global__ __launch_bounds__(256) void k_wprep(
    const float* s0, const float* b0, const float* a0,
    const float* s1, const float* b1, const float* a1,
    bf16* d0, bf16* d1, bf16* d2, bf16* d3, bf16* d4, bf16* d5)
{
  const int m = blockIdx.y;
  const int Kd = (m == 2) ? 320 : (m < 2 ? 384 : 512);
  const int total = 1024 * Kd;
  int idx = blockIdx.x * 256 + threadIdx.x;
  if (idx >= total) return;
  int n = idx / Kd, k = idx - n * Kd;
  const float* src = (m==0)?s0:(m==1)?b0:(m==2)?a0:(m==3)?s1:(m==4)?b1:a1;
  bf16* dst        = (m==0)?d0:(m==1)?d1:(m==2)?d2:(m==3)?d3:(m==4)?d4:d5;
  int ksrc = k;
  if (m == 2) ksrc = (k < 50) ? k : (k < 64 ? -1 : k - 14);
  float v = (ksrc >= 0) ? src[ksrc * 1024 + n] : 0.f;
  dst[n * Kd + k] = (bf16)v;
}

// =====================================================================
// Kernel 3: batch-split LSTM — NO inter-block communication.
// 24 active blocks (grid 64, XCD-partitioned via bx&7): each owns 16
// batch rows of one LSTM and runs the full 2-layer recurrence.  h/c in
// regs; h published to LDS (bf16, stride 280 = 2-way-conflict b128) for
// cross-wave A-fragments; W^T streamed from L2 (1.6-1.8 MB/step/block).
// 512 threads: wave wv owns u-cols wv*32..+32 across all 4 gates.
// =====================================================================
__global__ __launch_bounds__(512) void k_lstm2(
    const bf16* w0s, const bf16* w0b, const bf16* w0a,
    const bf16* w1s, const bf16* w1b, const bf16* w1a,
    const float* sb0, const float* sb1, const float* bb0, const float* bb1,
    const float* ab0, const float* ab1,
    const bf16* stack_emb, const bf16* buff_emb,
    const float* hist_tab, const int* hist_id,
    const int* len_s, const int* len_b, const int* len_a,
    bf16* h1out)
{
  // XCD partition: stack -> xcd 0-2, buffer -> 3-4, action -> 5-7.
  const int bx = blockIdx.x;
  const int xcd = bx & 7, r = bx >> 3;
  int L, slice;
  if (xcd < 3)      { L = 0; slice = r * 3 + xcd; }
  else if (xcd < 5) { L = 1; slice = r * 2 + (xcd - 3); }
  else              { L = 2; slice = r * 3 + (xcd - 5); }
  if (slice >= 8) return;

  const bf16* W0T  = (L == 0) ? w0s : (L == 1) ? w0b : w0a;
  const bf16* W1T  = (L == 0) ? w1s : (L == 1) ? w1b : w1a;
  const float* B0  = (L == 0) ? sb0 : (L == 1) ? bb0 : ab0;
  const float* B1  = (L == 0) ? sb1 : (L == 1) ? bb1 : ab1;
  const int* lenp  = (L == 0) ? len_s : (L == 1) ? len_b : len_a;
  const int T      = (L == 0) ? STK : (L == 1) ? BUFF : HIST;
  const int K0p    = (L == 2) ? 320 : 384;
  const bf16* xsrc = (L == 0) ? stack_emb : buff_emb;
  const int Tx     = (L == 0) ? STK : BUFF;

  __shared__ __align__(16) bf16 h0s[2][16][280];
  __shared__ __align__(16) bf16 h1s[2][16][280];
  __shared__ __align__(16) bf16 Xa[16][88];

  const int tid = threadIdx.x;
  const int wv = tid >> 6, lane = tid & 63, l15 = lane & 15, quad = lane >> 4;

  for (int i = tid; i < 2 * 16 * 280; i += 512) {
    ((bf16*)h0s)[i] = (bf16)0.f;
    ((bf16*)h1s)[i] = (bf16)0.f;
  }

  float bia0[8], bia1[8];
#pragma unroll
  for (int nt = 0; nt < 8; ++nt) {
    int col = (nt >> 1) * 256 + wv * 32 + (nt & 1) * 16 + l15;
    bia0[nt] = B0[col]; bia1[nt] = B1[col];
  }
  int lenr[4];
#pragma unroll
  for (int rr = 0; rr < 4; ++rr) lenr[rr] = lenp[slice * 16 + quad * 4 + rr];

  float c0[8], h0v[8], c1[8], h1v[8];
#pragma unroll
  for (int i = 0; i < 8; ++i) { c0[i] = h0v[i] = c1[i] = h1v[i] = 0.f; }

  for (int t = 0; t < T; ++t) {
    const int pt = t & 1, pr = pt ^ 1;

    if (L == 2) {  // stage action x_t (50 fp32 -> 64 bf16, zero-padded)
      int row = tid >> 5, e0 = (tid & 31) * 2;
      int id = hist_id[(slice * 16 + row) * HIST + t];
      unsigned v = 0u;
      if (e0 < 50) v = pack2(hist_tab + id * 50 + e0);
      *(unsigned*)(&Xa[row][e0]) = v;
    }
    __syncthreads();  // Xa + h(prev step) + (t==0) zero-init visible

    // ---- layer 0 ----
    f32x4 acc[8];
#pragma unroll
    for (int i = 0; i < 8; ++i) acc[i] = (f32x4){0.f, 0.f, 0.f, 0.f};

    if (L == 2) {
#pragma unroll
      for (int ks = 0; ks < 10; ++ks) {
        int kq = ks * 32 + quad * 8;
        bf16x8 a = (ks < 2) ? *(const bf16x8*)(&Xa[l15][kq])
                            : *(const bf16x8*)(&h0s[pr][l15][kq - 64]);
#pragma unroll
        for (int nt = 0; nt < 8; ++nt) {
          int n0 = (nt >> 1) * 256 + wv * 32 + (nt & 1) * 16;
          bf16x8 b = *(const bf16x8*)(W0T + (n0 + l15) * 320 + kq);
          acc[nt] = __builtin_amdgcn_mfma_f32_16x16x32_bf16(a, b, acc[nt], 0, 0, 0);
        }
      }
    } else {
#pragma unroll
      for (int ks = 0; ks < 12; ++ks) {
        int kq = ks * 32 + quad * 8;
        bf16x8 a = (ks < 4)
          ? *(const bf16x8*)(xsrc + ((slice * 16 + l15) * Tx + t) * 128 + kq)
          : *(const bf16x8*)(&h0s[pr][l15][kq - 128]);
#pragma unroll
        for (int nt = 0; nt < 8; ++nt) {
          int n0 = (nt >> 1) * 256 + wv * 32 + (nt & 1) * 16;
          bf16x8 b = *(const bf16x8*)(W0T + (n0 + l15) * 384 + kq);
          acc[nt] = __builtin_amdgcn_mfma_f32_16x16x32_bf16(a, b, acc[nt], 0, 0, 0);
        }
      }
    }
#pragma unroll
    for (int t16 = 0; t16 < 2; ++t16)
#pragma unroll
      for (int rr = 0; rr < 4; ++rr) {
        float zi = acc[0 + t16][rr] + bia0[0 + t16];
        float zj = acc[2 + t16][rr] + bia0[2 + t16];
        float zf = acc[4 + t16][rr] + bia0[4 + t16];
        float zo = acc[6 + t16][rr] + bia0[6 + t16];
        float ig = sigf(zi), jg = tanhf_(zj), fg = sigf(zf + 1.f), og = sigf(zo);
        int idx = t16 * 4 + rr;
        float cn = c0[idx] * fg + ig * jg;
        float hn = tanhf_(cn) * og;
        bool mk = (t < lenr[rr]);
        c0[idx]  = mk ? cn : c0[idx];
        h0v[idx] = mk ? hn : h0v[idx];
        h0s[pt][quad * 4 + rr][wv * 32 + t16 * 16 + l15] = (bf16)h0v[idx];
      }
    __syncthreads();  // h0[pt] published

    // ---- layer 1 ----
#pragma unroll
    for (int i = 0; i < 8; ++i) acc[i] = (f32x4){0.f, 0.f, 0.f, 0.f};
#pragma unroll
    for (int ks = 0; ks < 16; ++ks) {
      int kq = ks * 32 + quad * 8;
      bf16x8 a = (ks < 8) ? *(const bf16x8*)(&h0s[pt][l15][kq])
                          : *(const bf16x8*)(&h1s[pr][l15][kq - 256]);
#pragma unroll
      for (int nt = 0; nt < 8; ++nt) {
        int n0 = (nt >> 1) * 256 + wv * 32 + (nt & 1) * 16;
        bf16x8 b = *(const bf16x8*)(W1T + (n0 + l15) * 512 + kq);
        acc[nt] = __builtin_amdgcn_mfma_f32_16x16x32_bf16(a, b, acc[nt], 0, 0, 0);
      }
    }
#pragma unroll
    for (int t16 = 0; t16 < 2; ++t16)
#pragma unroll
      for (int rr = 0; rr < 4; ++rr) {
        float zi = acc[0 + t16][rr] + bia1[0 + t16];
        float zj = acc[2 + t16][rr] + bia1[2 + t16];
        float zf = acc[4 + t16][rr] + bia1[4 + t16];
        float zo = acc[6 + t16][rr] + bia1[6 + t16];
        float ig = sigf(zi), jg = tanhf_(zj), fg = sigf(zf + 1.f), og = sigf(zo);
        int idx = t16 * 4 + rr;
        float cn = c1[idx] * fg + ig * jg;
        float hn = tanhf_(cn) * og;
        bool mk = (t < lenr[rr]);
        c1[idx]  = mk ? cn : c1[idx];
        h1v[idx] = mk ? hn : h1v[idx];
        h1s[pt][quad * 4 + rr][wv * 32 + t16 * 16 + l15] = (bf16)h1v[idx];
      }
    __syncthreads();  // h1[pt] published; safe to restage Xa next step
  }

  // final h1 -> global
#pragma unroll
  for (int t16 = 0; t16 < 2; ++t16)
#pragma unroll
    for (int rr = 0; rr < 4; ++rr)
      h1out[L * 32768 + (slice * 16 + quad * 4 + rr) * 256 + wv * 32 + t16 * 16 + l15] =
          (bf16)h1v[t16 * 4 + rr];
}

// =====================================================================
// Kernel 4: out = concat(h_s,h_b,h_a) @ fW + fb
// =====================================================================
__global__ __launch_bounds__(128) void k_final(
    const bf16* h1buf, const float* fW, const float* fb, float* out)
{
  __shared__ float hs[768];
  const int b = blockIdx.x, tid = threadIdx.x;
  for (int i = tid; i < 768; i += 128) {
    int Li = i >> 8, u = i & 255;
    hs[i] = (float)h1buf[Li * 32768 + b * 256 + u];
  }
  __syncthreads();
  if (tid < NOUT) {
    float acc = fb[tid];
    for (int u = 0; u < 768; ++u) acc += hs[u] * fW[u * NOUT + tid];
    out[b * NOUT + tid] = acc;
  }
}

// =====================================================================
extern "C" void kernel_launch(void* const* d_in, const int* in_sizes, int n_in,
                              void* d_out, int out_size, void* d_ws, size_t ws_size,
                              hipStream_t stream)
{
  (void)in_sizes; (void)n_in; (void)out_size; (void)ws_size;
  char* ws = (char*)d_ws;
  bf16* h1buf     = (bf16*)ws;                                  // 196608 B
  bf16* comp_emb  = (bf16*)(ws + 786944);                       // 25165824 B
  // W^T aliases comp_emb (dead after k_compose): 5373952 B total
  bf16* wT_s0 = (bf16*)(ws + 786944);
  bf16* wT_b0 = (bf16*)(ws + 786944 + 786432);
  bf16* wT_a0 = (bf16*)(ws + 786944 + 1572864);
  bf16* wT_s1 = (bf16*)(ws + 786944 + 2228224);
  bf16* wT_b1 = (bf16*)(ws + 786944 + 3276800);
  bf16* wT_a1 = (bf16*)(ws + 786944 + 4325376);
  bf16* buff_emb  = (bf16*)(ws + 786944 + 25165824);            // 2097152 B
  bf16* stack_emb = (bf16*)(ws + 786944 + 25165824 + 2097152);  // 1572864 B

  k_emb<<<1664, 256, 0, stream>>>(
      (const int*)d_in[0], (const int*)d_in[1], (const int*)d_in[2], (const int*)d_in[3],
      (const float*)d_in[13], (const float*)d_in[10], (const float*)d_in[14], (const float*)d_in[15],
      comp_emb, buff_emb);

  k_compose<<<384, 256, 0, stream>>>(
      (const int*)d_in[2], (const int*)d_in[4], (const int*)d_in[5],
      comp_emb, (const float*)d_in[11], (const float*)d_in[16], (const float*)d_in[17],
      stack_emb);

  k_wprep<<<dim3(2048, 6), 256, 0, stream>>>(
      (const float*)d_in[18], (const float*)d_in[22], (const float*)d_in[26],
      (const float*)d_in[20], (const float*)d_in[24], (const float*)d_in[28],
      wT_s0, wT_b0, wT_a0, wT_s1, wT_b1, wT_a1);

  k_lstm2<<<64, 512, 0, stream>>>(
      wT_s0, wT_b0, wT_a0, wT_s1, wT_b1, wT_a1,
      (const float*)d_in[19], (const float*)d_in[21],
      (const float*)d_in[23], (const float*)d_in[25],
      (const float*)d_in[27], (const float*)d_in[29],
      stack_emb, buff_emb, (const float*)d_in[12], (const int*)d_in[6],
      (const int*)d_in[7], (const int*)d_in[8], (const int*)d_in[9],
      h1buf);

  k_final<<<128, 128, 0, stream>>>(h1buf, (const float*)d_in[30], (const float*)d_in[31],
                                   (float*)d_out);
}

// Round 7
// 2852.641 us; speedup vs baseline: 1.9331x; 1.9331x over previous
//
#include <hip/hip_runtime.h>

// ---------------- problem constants ----------------
#define BUFF  64
#define STK   48
#define HIST  96
#define NOUT  82

typedef __bf16 bf16;
typedef __attribute__((ext_vector_type(8))) __bf16 bf16x8;
typedef __attribute__((ext_vector_type(4))) float   f32x4;

__device__ __forceinline__ float sigf(float x)   { return 1.f / (1.f + __expf(-x)); }
__device__ __forceinline__ float tanhf_(float x) { return 1.f - 2.f / (1.f + __expf(2.f * x)); }

__device__ __forceinline__ unsigned pack2(const float* p) {
  union { unsigned u; bf16 h[2]; } r;
  r.h[0] = (bf16)p[0]; r.h[1] = (bf16)p[1];
  return r.u;
}

// volatile = sc0: bypass L1, read/write the XCD's L2 (NOT sc1/MALL).
__device__ __forceinline__ bf16x8 vload16(const bf16* p) {
  union { unsigned long long q[2]; bf16x8 v; } u;
  const volatile unsigned long long* vp = (const volatile unsigned long long*)p;
  u.q[0] = vp[0];
  u.q[1] = vp[1];
  return u.v;
}
__device__ __forceinline__ void vstore8(bf16* p, unsigned long long v) {
  *(volatile unsigned long long*)p = v;
}

// =====================================================================
// Kernel 1: embedding MLP (unchanged, proven).
// =====================================================================
__global__ __launch_bounds__(256) void k_emb(
    const int* bw, const int* bp, const int* cw, const int* cp,
    const float* w_emb, const float* p_emb, const float* embW, const float* embB,
    bf16* comp_emb, bf16* buff_emb)
{
  __shared__ __align__(16) char sm[138752];
  bf16*  A  = (bf16*)sm;                    // [64][360]
  bf16*  Wt = (bf16*)(sm + 46080);          // [128][360]
  float* sb = (float*)(sm + 46080 + 92160); // [128]

  const int tid = threadIdx.x;
  const int r0  = blockIdx.x * 64;

  for (int i = tid; i < 64 * 176; i += 256) {
    int m = i / 176, c2 = i % 176, e0 = 2 * c2;
    int r = r0 + m;
    unsigned v;
    if (e0 < 300) {
      int word = (r < 98304) ? cw[r] : bw[r - 98304];
      v = pack2(w_emb + word * 300 + e0);
    } else if (e0 < 350) {
      int pos = (r < 98304) ? cp[r] : bp[r - 98304];
      v = pack2(p_emb + pos * 50 + (e0 - 300));
    } else v = 0u;
    *(unsigned*)(A + m * 360 + e0) = v;
  }
  for (int i = tid; i < 350 * 128; i += 256) {
    int k = i >> 7, n = i & 127;
    Wt[n * 360 + k] = (bf16)embW[i];
  }
  { int i = tid; if (i < 256) { int n = i >> 1; Wt[n * 360 + 350 + (i & 1)] = (bf16)0.f; } }
  if (tid < 128) sb[tid] = embB[tid];
  __syncthreads();

  const int wv = tid >> 6, lane = tid & 63, l15 = lane & 15, quad = lane >> 4;
  f32x4 acc[8];
#pragma unroll
  for (int i = 0; i < 8; ++i) acc[i] = (f32x4){0.f, 0.f, 0.f, 0.f};

  const bf16* Arow = A + (wv * 16 + l15) * 360;
  for (int ks = 0; ks < 11; ++ks) {
    int kq = ks * 32 + quad * 8;
    bf16x8 a = *(const bf16x8*)(Arow + kq);
#pragma unroll
    for (int nt = 0; nt < 8; ++nt) {
      bf16x8 b = *(const bf16x8*)(Wt + (nt * 16 + l15) * 360 + kq);
      acc[nt] = __builtin_amdgcn_mfma_f32_16x16x32_bf16(a, b, acc[nt], 0, 0, 0);
    }
  }
#pragma unroll
  for (int nt = 0; nt < 8; ++nt)
#pragma unroll
    for (int rr = 0; rr < 4; ++rr) {
      int row = wv * 16 + quad * 4 + rr;
      int n   = nt * 16 + l15;
      float z = fmaxf(acc[nt][rr] + sb[n], 0.f);
      int r = r0 + row;
      bf16 o = (bf16)z;
      if (r < 98304) comp_emb[r * 128 + n] = o;
      else           buff_emb[(r - 98304) * 128 + n] = o;
    }
}

// =====================================================================
// Kernel 2: compose (unchanged, proven).
// =====================================================================
__global__ __launch_bounds__(256) void k_compose(
    const int* cw, const int* caid, const int* calen,
    const bf16* comp_emb, const float* ca_emb, const float* recW, const float* recB,
    bf16* stack_emb)
{
  __shared__ __align__(16) char sm[129344];
  bf16*  Wt   = (bf16*)sm;              // [128][328]
  bf16*  X    = (bf16*)(sm + 83968);    // [16][328]
  bf16*  VALS = (bf16*)(sm + 94464);    // [16][8][128]
  float* recb = (float*)(sm + 127232);  // [128]
  int*   IH   = (int*)(sm + 127744);
  int*   ID   = (int*)(sm + 128256);
  int*   AN   = (int*)(sm + 128768);
  int*   ALEN = (int*)(sm + 129280);

  const int tid = threadIdx.x;
  const int bs0 = blockIdx.x * 16;

  for (int i = tid; i < 306 * 128; i += 256) {
    int k = i >> 7, n = i & 127;
    Wt[n * 328 + k] = (bf16)recW[i];
  }
  for (int i = tid; i < 128 * 22; i += 256) {
    int n = i / 22, k = 306 + i % 22;
    Wt[n * 328 + k] = (bf16)0.f;
  }
  if (tid < 128) recb[tid] = recB[tid];
  if (tid < 16) {
    int bs = bs0 + tid;
    int hid[8], did[8];
#pragma unroll
    for (int m = 0; m < 8; ++m) { hid[m] = cw[bs * 16 + 2 * m]; did[m] = cw[bs * 16 + 2 * m + 1]; }
    for (int n = 0; n < 8; ++n) {
      int ih = -1, idd = -1;
      for (int m = 0; m < n; ++m) { if (hid[m] == hid[n]) ih = m; if (hid[m] == did[n]) idd = m; }
      IH[tid * 8 + n] = ih; ID[tid * 8 + n] = idd; AN[tid * 8 + n] = caid[bs * 8 + n];
    }
    ALEN[tid] = calen[bs];
  }
  __syncthreads();

  const int wv = tid >> 6, lane = tid & 63, l15 = lane & 15, quad = lane >> 4;

  for (int n = 0; n < 8; ++n) {
    for (int i = tid; i < 16 * 160; i += 256) {
      int p = i / 160, c2 = i % 160, e0 = 2 * c2;
      int bs = bs0 + p;
      unsigned v;
      if (e0 < 128) {
        int ih = IH[p * 8 + n];
        v = (ih >= 0) ? *(const unsigned*)(VALS + (p * 8 + ih) * 128 + e0)
                      : *(const unsigned*)(comp_emb + (bs * 16 + 2 * n) * 128 + e0);
      } else if (e0 < 178) {
        v = pack2(ca_emb + AN[p * 8 + n] * 50 + (e0 - 128));
      } else if (e0 < 306) {
        int e = e0 - 178;
        int idd = ID[p * 8 + n];
        v = (idd >= 0) ? *(const unsigned*)(VALS + (p * 8 + idd) * 128 + e)
                       : *(const unsigned*)(comp_emb + (bs * 16 + 2 * n + 1) * 128 + e);
      } else v = 0u;
      *(unsigned*)(X + p * 328 + e0) = v;
    }
    __syncthreads();

    f32x4 acc[2];
    acc[0] = (f32x4){0.f,0.f,0.f,0.f}; acc[1] = (f32x4){0.f,0.f,0.f,0.f};
    for (int ks = 0; ks < 10; ++ks) {
      int kq = ks * 32 + quad * 8;
      bf16x8 a = *(const bf16x8*)(X + l15 * 328 + kq);
#pragma unroll
      for (int t2 = 0; t2 < 2; ++t2) {
        int nt = 2 * wv + t2;
        bf16x8 b = *(const bf16x8*)(Wt + (nt * 16 + l15) * 328 + kq);
        acc[t2] = __builtin_amdgcn_mfma_f32_16x16x32_bf16(a, b, acc[t2], 0, 0, 0);
      }
    }
    __syncthreads();
#pragma unroll
    for (int t2 = 0; t2 < 2; ++t2) {
      int nt = 2 * wv + t2;
#pragma unroll
      for (int rr = 0; rr < 4; ++rr) {
        int p = quad * 4 + rr;
        int col = nt * 16 + l15;
        VALS[(p * 8 + n) * 128 + col] = (bf16)tanhf_(acc[t2][rr] + recb[col]);
      }
    }
    __syncthreads();
  }

  for (int i = tid; i < 16 * 64; i += 256) {
    int p = i / 64, c2 = i % 64, e0 = 2 * c2;
    int bs = bs0 + p;
    int al = ALEN[p];
    unsigned v = (al == 0) ? *(const unsigned*)(comp_emb + (bs * 16) * 128 + e0)
                           : *(const unsigned*)(VALS + (p * 8 + (al - 1)) * 128 + e0);
    *(unsigned*)(stack_emb + bs * 128 + e0) = v;
  }
}

// =====================================================================
// Kernel 3: persistent u-split LSTM, SAME-XCD edition.
// Blocks read their physical XCD id (s_getreg HW_REG_XCC_ID, HW-verified)
// and claim roles per-XCD: LSTM L's 16 blocks all live on XCD L, so
// h-exchange + barrier stay inside ONE L2:
//   - h stores/loads: volatile (sc0) = L1-bypass, L2-hit (~200cyc, not
//     sc1/MALL ~900cyc which cost R3 ~13us/phase)
//   - barrier: workgroup-scope global_atomic_add (executes in local L2)
//     + volatile poll; monotone counter, no acquire/release.
// W stays resident in LDS (R3 layout) — R6 proved streaming W through
// one CU is a 4x loss.  Each counter gets its own 256B line (cross-XCD
// dirty-line writeback hazard).
// =====================================================================
struct __align__(256) Ctr { int cnt; int pad[63]; };

__global__ __launch_bounds__(256) void k_lstm3(
    const float* sW0, const float* sb0, const float* sW1, const float* sb1,
    const float* bW0, const float* bb0, const float* bW1, const float* bb1,
    const float* aW0, const float* ab0, const float* aW1, const float* ab1,
    const bf16* stack_emb, const bf16* buff_emb, const float* hist_tab, const int* hist_id,
    const int* len_s, const int* len_b, const int* len_a,
    bf16* h0buf, bf16* h1buf, bf16* h1out, Ctr* claims, Ctr* bars)
{
  __shared__ __align__(16) char sm[143872];
  __shared__ int role_sh;
  const int tid = threadIdx.x;

  unsigned xcc;
  asm volatile("s_getreg_b32 %0, hwreg(HW_REG_XCC_ID)" : "=s"(xcc));
  if (tid == 0) {
    int rr = -1;
    if (xcc < 3)
      rr = __hip_atomic_fetch_add(&claims[xcc].cnt, 1, __ATOMIC_RELAXED,
                                  __HIP_MEMORY_SCOPE_WORKGROUP);
    role_sh = (rr >= 0 && rr < 16) ? rr : -1;
  }
  __syncthreads();
  const int rid = role_sh;
  if (rid < 0) return;

  const int L     = (int)xcc;
  const int layer = rid >> 3;
  const int u0    = (rid & 7) * 32;
  const int T     = (L == 0) ? STK : (L == 1) ? BUFF : HIST;
  const int* lenp = (L == 0) ? len_s : (L == 1) ? len_b : len_a;

  const float *W, *bias;
  int K, KP, Kxp;
  if (layer == 0) {
    W = (L == 0) ? sW0 : (L == 1) ? bW0 : aW0;
    bias = (L == 0) ? sb0 : (L == 1) ? bb0 : ab0;
    if (L == 2) { K = 320; KP = 328; Kxp = 64; } else { K = 384; KP = 392; Kxp = 128; }
  } else {
    W = (L == 0) ? sW1 : (L == 1) ? bW1 : aW1;
    bias = (L == 0) ? sb1 : (L == 1) ? bb1 : ab1;
    K = 512; KP = 520; Kxp = 256;
  }
  bf16*  Wt     = (bf16*)sm;                               // [128][KP]
  bf16*  hstage = (bf16*)(sm + 128 * KP * 2);              // [128][36]
  float* sb     = (float*)(sm + 128 * KP * 2 + 9216);      // [128]
  bf16*  Xa     = (bf16*)(sm + 128 * KP * 2 + 9216 + 512); // [128][72] (action L0)

  for (int i = tid; i < K * 128; i += 256) {
    int kk = i >> 7, cc = i & 127;
    int col = (cc >> 5) * 256 + u0 + (cc & 31);
    bf16 v;
    if (layer == 0 && L == 2) {
      if (kk < 64) v = (kk < 50) ? (bf16)W[kk * 1024 + col] : (bf16)0.f;
      else         v = (bf16)W[(kk - 14) * 1024 + col];
    } else v = (bf16)W[kk * 1024 + col];
    Wt[cc * KP + kk] = v;
  }
  if (tid < 128) { int col = (tid >> 5) * 256 + u0 + (tid & 31); sb[tid] = bias[col]; }

  const int wv = tid >> 6, lane = tid & 63, l15 = lane & 15, quad = lane >> 4;
  int lenr[8];
#pragma unroll
  for (int mt = 0; mt < 2; ++mt)
#pragma unroll
    for (int rr = 0; rr < 4; ++rr)
      lenr[mt * 4 + rr] = lenp[32 * wv + 16 * mt + quad * 4 + rr];

  float cst[16], hst[16];
#pragma unroll
  for (int i = 0; i < 16; ++i) { cst[i] = 0.f; hst[i] = 0.f; }

  Ctr* bar = bars + L;
  bf16* h0w = h0buf + L * 2 * 32768;  // [2][128][256]
  bf16* h1w = h1buf + L * 2 * 32768;
  const bf16* xsrc = (L == 0) ? stack_emb : buff_emb;
  const int Tx = (L == 0) ? STK : BUFF;

  __syncthreads();

  for (int p = 0; p <= T; ++p) {
    const bool active = (layer == 0) ? (p < T) : (p >= 1);
    const int  t = (layer == 0) ? p : (p - 1);

    if (L == 2 && layer == 0 && active) {  // stage action x_t (50 -> 64 padded)
      for (int i = tid; i < 128 * 32; i += 256) {
        int row = i >> 5, e0 = 2 * (i & 31);
        unsigned v = 0u;
        if (e0 < 50) { int id = hist_id[row * 96 + t]; v = pack2(hist_tab + id * 50 + e0); }
        *(unsigned*)(Xa + row * 72 + e0) = v;
      }
    }
    __syncthreads();

    if (active) {
      f32x4 acc[2][8];
#pragma unroll
      for (int a1 = 0; a1 < 2; ++a1)
#pragma unroll
        for (int a2 = 0; a2 < 8; ++a2) acc[a1][a2] = (f32x4){0.f, 0.f, 0.f, 0.f};

      const bf16* h0r = h0w + ((p - 1) & 1) * 32768;
      const bf16* h1r = h1w + (p & 1) * 32768;

      for (int ks = 0; ks < K / 32; ++ks) {
        int k0 = ks * 32;
        int kq = k0 + quad * 8;
        bf16x8 a[2];
#pragma unroll
        for (int mt = 0; mt < 2; ++mt) {
          int row = 32 * wv + 16 * mt + l15;
          if (layer == 0) {
            if (k0 < Kxp) {
              if (L == 2) a[mt] = *(const bf16x8*)(Xa + row * 72 + kq);
              else        a[mt] = *(const bf16x8*)(xsrc + (row * Tx + t) * 128 + kq);
            } else a[mt] = vload16(h0r + row * 256 + (kq - Kxp));
          } else {
            if (k0 < 256) a[mt] = vload16(h0r + row * 256 + kq);
            else          a[mt] = vload16(h1r + row * 256 + (kq - 256));
          }
        }
#pragma unroll
        for (int nt = 0; nt < 8; ++nt) {
          bf16x8 b = *(const bf16x8*)(Wt + (nt * 16 + l15) * KP + kq);
          acc[0][nt] = __builtin_amdgcn_mfma_f32_16x16x32_bf16(a[0], b, acc[0][nt], 0, 0, 0);
          acc[1][nt] = __builtin_amdgcn_mfma_f32_16x16x32_bf16(a[1], b, acc[1][nt], 0, 0, 0);
        }
      }
      // gates: nt 0,1 = i ; 2,3 = j ; 4,5 = f ; 6,7 = o
#pragma unroll
      for (int mt = 0; mt < 2; ++mt)
#pragma unroll
        for (int g2 = 0; g2 < 2; ++g2)
#pragma unroll
          for (int rr = 0; rr < 4; ++rr) {
            int row = 32 * wv + 16 * mt + quad * 4 + rr;
            float zi = acc[mt][0 + g2][rr] + sb[(0 + g2) * 16 + l15];
            float zj = acc[mt][2 + g2][rr] + sb[(2 + g2) * 16 + l15];
            float zf = acc[mt][4 + g2][rr] + sb[(4 + g2) * 16 + l15];
            float zo = acc[mt][6 + g2][rr] + sb[(6 + g2) * 16 + l15];
            float ig = sigf(zi), jg = tanhf_(zj), fg = sigf(zf + 1.f), og = sigf(zo);
            int idx = mt * 8 + g2 * 4 + rr;
            float cn = cst[idx] * fg + ig * jg;
            float hn = tanhf_(cn) * og;
            bool mk = (t < lenr[mt * 4 + rr]);
            cst[idx] = mk ? cn : cst[idx];
            hst[idx] = mk ? hn : hst[idx];
            hstage[row * 36 + g2 * 16 + l15] = (bf16)hst[idx];
          }
    }
    __syncthreads();
    if (active) {
      bf16* dst = (layer == 0) ? (h0w + (p & 1) * 32768) : (h1w + ((p - 1) & 1) * 32768);
      for (int i = tid; i < 128 * 8; i += 256) {
        int row = i >> 3, c = i & 7;
        unsigned long long v = *(const unsigned long long*)(hstage + row * 36 + c * 4);
        vstore8(dst + row * 256 + u0 + c * 4, v);
      }
    }
    // same-XCD barrier: L2-local atomic + volatile (sc0) poll.
    __syncthreads();  // drains vmcnt -> h stores are in L2 before arrival
    if (tid == 0) {
      __hip_atomic_fetch_add(&bar->cnt, 1, __ATOMIC_RELAXED, __HIP_MEMORY_SCOPE_WORKGROUP);
      const int target = 16 * (p + 1);
      while (*(volatile int*)&bar->cnt < target) { }
    }
    __syncthreads();
  }

  // final h1 -> compact h1out (layer-1 blocks own their 32 cols x all rows)
  if (layer == 1) {
#pragma unroll
    for (int mt = 0; mt < 2; ++mt)
#pragma unroll
      for (int g2 = 0; g2 < 2; ++g2)
#pragma unroll
        for (int rr = 0; rr < 4; ++rr) {
          int row = 32 * wv + 16 * mt + quad * 4 + rr;
          h1out[L * 32768 + row * 256 + u0 + g2 * 16 + l15] = (bf16)hst[mt * 8 + g2 * 4 + rr];
        }
  }
}

// =====================================================================
// Kernel 4: out = concat(h_s,h_b,h_a) @ fW + fb
// =====================================================================
__global__ __launch_bounds__(128) void k_final(
    const bf16* h1out, const float* fW, const float* fb, float* out)
{
  __shared__ float hs[768];
  const int b = blockIdx.x, tid = threadIdx.x;
  for (int i = tid; i < 768; i += 128) {
    int Li = i >> 8, u = i & 255;
    hs[i] = (float)h1out[Li * 32768 + b * 256 + u];
  }
  __syncthreads();
  if (tid < NOUT) {
    float acc = fb[tid];
    for (int u = 0; u < 768; ++u) acc += hs[u] * fW[u * NOUT + tid];
    out[b * NOUT + tid] = acc;
  }
}

// =====================================================================
extern "C" void kernel_launch(void* const* d_in, const int* in_sizes, int n_in,
                              void* d_out, int out_size, void* d_ws, size_t ws_size,
                              hipStream_t stream)
{
  (void)in_sizes; (void)n_in; (void)out_size; (void)ws_size;
  char* ws = (char*)d_ws;
  bf16* h0buf     = (bf16*)(ws + 512);                     // 393216 B
  bf16* h1buf     = (bf16*)(ws + 512 + 393216);            // 393216 B (ends 786944)
  // control + h1out live in comp_emb's head (dead after k_compose):
  Ctr*  claims    = (Ctr*)(ws + 786944);                   // 3 x 256 B
  Ctr*  bars      = (Ctr*)(ws + 786944 + 1024);            // 3 x 256 B
  bf16* h1out     = (bf16*)(ws + 786944 + 4096);           // 196608 B
  bf16* comp_emb  = (bf16*)(ws + 786944);                  // 25165824 B
  bf16* buff_emb  = (bf16*)(ws + 786944 + 25165824);       // 2097152 B
  bf16* stack_emb = (bf16*)(ws + 786944 + 25165824 + 2097152); // 1572864 B

  hipMemsetAsync(ws, 0, 786944, stream);  // h0/h1 initial state

  k_emb<<<1664, 256, 0, stream>>>(
      (const int*)d_in[0], (const int*)d_in[1], (const int*)d_in[2], (const int*)d_in[3],
      (const float*)d_in[13], (const float*)d_in[10], (const float*)d_in[14], (const float*)d_in[15],
      comp_emb, buff_emb);

  k_compose<<<384, 256, 0, stream>>>(
      (const int*)d_in[2], (const int*)d_in[4], (const int*)d_in[5],
      comp_emb, (const float*)d_in[11], (const float*)d_in[16], (const float*)d_in[17],
      stack_emb);

  // comp_emb is dead now -> zero the claim/barrier control block
  hipMemsetAsync(ws + 786944, 0, 4096, stream);

  k_lstm3<<<512, 256, 0, stream>>>(
      (const float*)d_in[18], (const float*)d_in[19], (const float*)d_in[20], (const float*)d_in[21],
      (const float*)d_in[22], (const float*)d_in[23], (const float*)d_in[24], (const float*)d_in[25],
      (const float*)d_in[26], (const float*)d_in[27], (const float*)d_in[28], (const float*)d_in[29],
      stack_emb, buff_emb, (const float*)d_in[12], (const int*)d_in[6],
      (const int*)d_in[7], (const int*)d_in[8], (const int*)d_in[9],
      h0buf, h1buf, h1out, claims, bars);

  k_final<<<128, 128, 0, stream>>>(h1out, (const float*)d_in[30], (const float*)d_in[31],
                                   (float*)d_out);
}

// Round 8
// 2150.172 us; speedup vs baseline: 2.5647x; 1.3267x over previous
//
#include <hip/hip_runtime.h>

// ---------------- problem constants ----------------
#define BUFF  64
#define STK   48
#define HIST  96
#define NOUT  82

typedef __bf16 bf16;
typedef __attribute__((ext_vector_type(8))) __bf16 bf16x8;
typedef __attribute__((ext_vector_type(4))) float   f32x4;

__device__ __forceinline__ float sigf(float x)   { return 1.f / (1.f + __expf(-x)); }
__device__ __forceinline__ float tanhf_(float x) { return 1.f - 2.f / (1.f + __expf(2.f * x)); }

__device__ __forceinline__ unsigned pack2(const float* p) {
  union { unsigned u; bf16 h[2]; } r;
  r.h[0] = (bf16)p[0]; r.h[1] = (bf16)p[1];
  return r.u;
}

// producer-side h store: sc0 write-through (proven R7)
__device__ __forceinline__ void vstore8(bf16* p, unsigned long long v) {
  *(volatile unsigned long long*)p = v;
}
// consumer-side: invalidate this CU's vector L1 (local op, no traffic);
// subsequent PLAIN loads then miss L1 and hit the XCD's L2 fresh, fully
// pipelined (this replaces R7's serialized volatile loads).
__device__ __forceinline__ void inv_l1() {
  asm volatile("buffer_inv sc0" ::: "memory");
}

// =====================================================================
// Kernel 1: embedding MLP (unchanged, proven).
// =====================================================================
__global__ __launch_bounds__(256) void k_emb(
    const int* bw, const int* bp, const int* cw, const int* cp,
    const float* w_emb, const float* p_emb, const float* embW, const float* embB,
    bf16* comp_emb, bf16* buff_emb)
{
  __shared__ __align__(16) char sm[138752];
  bf16*  A  = (bf16*)sm;                    // [64][360]
  bf16*  Wt = (bf16*)(sm + 46080);          // [128][360]
  float* sb = (float*)(sm + 46080 + 92160); // [128]

  const int tid = threadIdx.x;
  const int r0  = blockIdx.x * 64;

  for (int i = tid; i < 64 * 176; i += 256) {
    int m = i / 176, c2 = i % 176, e0 = 2 * c2;
    int r = r0 + m;
    unsigned v;
    if (e0 < 300) {
      int word = (r < 98304) ? cw[r] : bw[r - 98304];
      v = pack2(w_emb + word * 300 + e0);
    } else if (e0 < 350) {
      int pos = (r < 98304) ? cp[r] : bp[r - 98304];
      v = pack2(p_emb + pos * 50 + (e0 - 300));
    } else v = 0u;
    *(unsigned*)(A + m * 360 + e0) = v;
  }
  for (int i = tid; i < 350 * 128; i += 256) {
    int k = i >> 7, n = i & 127;
    Wt[n * 360 + k] = (bf16)embW[i];
  }
  { int i = tid; if (i < 256) { int n = i >> 1; Wt[n * 360 + 350 + (i & 1)] = (bf16)0.f; } }
  if (tid < 128) sb[tid] = embB[tid];
  __syncthreads();

  const int wv = tid >> 6, lane = tid & 63, l15 = lane & 15, quad = lane >> 4;
  f32x4 acc[8];
#pragma unroll
  for (int i = 0; i < 8; ++i) acc[i] = (f32x4){0.f, 0.f, 0.f, 0.f};

  const bf16* Arow = A + (wv * 16 + l15) * 360;
  for (int ks = 0; ks < 11; ++ks) {
    int kq = ks * 32 + quad * 8;
    bf16x8 a = *(const bf16x8*)(Arow + kq);
#pragma unroll
    for (int nt = 0; nt < 8; ++nt) {
      bf16x8 b = *(const bf16x8*)(Wt + (nt * 16 + l15) * 360 + kq);
      acc[nt] = __builtin_amdgcn_mfma_f32_16x16x32_bf16(a, b, acc[nt], 0, 0, 0);
    }
  }
#pragma unroll
  for (int nt = 0; nt < 8; ++nt)
#pragma unroll
    for (int rr = 0; rr < 4; ++rr) {
      int row = wv * 16 + quad * 4 + rr;
      int n   = nt * 16 + l15;
      float z = fmaxf(acc[nt][rr] + sb[n], 0.f);
      int r = r0 + row;
      bf16 o = (bf16)z;
      if (r < 98304) comp_emb[r * 128 + n] = o;
      else           buff_emb[(r - 98304) * 128 + n] = o;
    }
}

// =====================================================================
// Kernel 2: compose (unchanged, proven).
// =====================================================================
__global__ __launch_bounds__(256) void k_compose(
    const int* cw, const int* caid, const int* calen,
    const bf16* comp_emb, const float* ca_emb, const float* recW, const float* recB,
    bf16* stack_emb)
{
  __shared__ __align__(16) char sm[129344];
  bf16*  Wt   = (bf16*)sm;              // [128][328]
  bf16*  X    = (bf16*)(sm + 83968);    // [16][328]
  bf16*  VALS = (bf16*)(sm + 94464);    // [16][8][128]
  float* recb = (float*)(sm + 127232);  // [128]
  int*   IH   = (int*)(sm + 127744);
  int*   ID   = (int*)(sm + 128256);
  int*   AN   = (int*)(sm + 128768);
  int*   ALEN = (int*)(sm + 129280);

  const int tid = threadIdx.x;
  const int bs0 = blockIdx.x * 16;

  for (int i = tid; i < 306 * 128; i += 256) {
    int k = i >> 7, n = i & 127;
    Wt[n * 328 + k] = (bf16)recW[i];
  }
  for (int i = tid; i < 128 * 22; i += 256) {
    int n = i / 22, k = 306 + i % 22;
    Wt[n * 328 + k] = (bf16)0.f;
  }
  if (tid < 128) recb[tid] = recB[tid];
  if (tid < 16) {
    int bs = bs0 + tid;
    int hid[8], did[8];
#pragma unroll
    for (int m = 0; m < 8; ++m) { hid[m] = cw[bs * 16 + 2 * m]; did[m] = cw[bs * 16 + 2 * m + 1]; }
    for (int n = 0; n < 8; ++n) {
      int ih = -1, idd = -1;
      for (int m = 0; m < n; ++m) { if (hid[m] == hid[n]) ih = m; if (hid[m] == did[n]) idd = m; }
      IH[tid * 8 + n] = ih; ID[tid * 8 + n] = idd; AN[tid * 8 + n] = caid[bs * 8 + n];
    }
    ALEN[tid] = calen[bs];
  }
  __syncthreads();

  const int wv = tid >> 6, lane = tid & 63, l15 = lane & 15, quad = lane >> 4;

  for (int n = 0; n < 8; ++n) {
    for (int i = tid; i < 16 * 160; i += 256) {
      int p = i / 160, c2 = i % 160, e0 = 2 * c2;
      int bs = bs0 + p;
      unsigned v;
      if (e0 < 128) {
        int ih = IH[p * 8 + n];
        v = (ih >= 0) ? *(const unsigned*)(VALS + (p * 8 + ih) * 128 + e0)
                      : *(const unsigned*)(comp_emb + (bs * 16 + 2 * n) * 128 + e0);
      } else if (e0 < 178) {
        v = pack2(ca_emb + AN[p * 8 + n] * 50 + (e0 - 128));
      } else if (e0 < 306) {
        int e = e0 - 178;
        int idd = ID[p * 8 + n];
        v = (idd >= 0) ? *(const unsigned*)(VALS + (p * 8 + idd) * 128 + e)
                       : *(const unsigned*)(comp_emb + (bs * 16 + 2 * n + 1) * 128 + e);
      } else v = 0u;
      *(unsigned*)(X + p * 328 + e0) = v;
    }
    __syncthreads();

    f32x4 acc[2];
    acc[0] = (f32x4){0.f,0.f,0.f,0.f}; acc[1] = (f32x4){0.f,0.f,0.f,0.f};
    for (int ks = 0; ks < 10; ++ks) {
      int kq = ks * 32 + quad * 8;
      bf16x8 a = *(const bf16x8*)(X + l15 * 328 + kq);
#pragma unroll
      for (int t2 = 0; t2 < 2; ++t2) {
        int nt = 2 * wv + t2;
        bf16x8 b = *(const bf16x8*)(Wt + (nt * 16 + l15) * 328 + kq);
        acc[t2] = __builtin_amdgcn_mfma_f32_16x16x32_bf16(a, b, acc[t2], 0, 0, 0);
      }
    }
    __syncthreads();
#pragma unroll
    for (int t2 = 0; t2 < 2; ++t2) {
      int nt = 2 * wv + t2;
#pragma unroll
      for (int rr = 0; rr < 4; ++rr) {
        int p = quad * 4 + rr;
        int col = nt * 16 + l15;
        VALS[(p * 8 + n) * 128 + col] = (bf16)tanhf_(acc[t2][rr] + recb[col]);
      }
    }
    __syncthreads();
  }

  for (int i = tid; i < 16 * 64; i += 256) {
    int p = i / 64, c2 = i % 64, e0 = 2 * c2;
    int bs = bs0 + p;
    int al = ALEN[p];
    unsigned v = (al == 0) ? *(const unsigned*)(comp_emb + (bs * 16) * 128 + e0)
                           : *(const unsigned*)(VALS + (p * 8 + (al - 1)) * 128 + e0);
    *(unsigned*)(stack_emb + bs * 128 + e0) = v;
  }
}

// =====================================================================
// Kernel 3: persistent u-split LSTM, same-XCD edition (R7 architecture,
// proven: FETCH 128->20MB).  R8 change: consumer loads are PLAIN loads
// preceded by one buffer_inv sc0 (L1 invalidate) per phase — R7's
// volatile loads were serialized by the compiler (one vmcnt(0) each,
// ~64 x 250cyc/phase).  Producer stores + L2-local barrier unchanged.
// =====================================================================
struct __align__(256) Ctr { int cnt; int pad[63]; };

__global__ __launch_bounds__(256) void k_lstm3(
    const float* sW0, const float* sb0, const float* sW1, const float* sb1,
    const float* bW0, const float* bb0, const float* bW1, const float* bb1,
    const float* aW0, const float* ab0, const float* aW1, const float* ab1,
    const bf16* stack_emb, const bf16* buff_emb, const float* hist_tab, const int* hist_id,
    const int* len_s, const int* len_b, const int* len_a,
    bf16* h0buf, bf16* h1buf, bf16* h1out, Ctr* claims, Ctr* bars)
{
  __shared__ __align__(16) char sm[143872];
  __shared__ int role_sh;
  const int tid = threadIdx.x;

  unsigned xcc;
  asm volatile("s_getreg_b32 %0, hwreg(HW_REG_XCC_ID)" : "=s"(xcc));
  if (tid == 0) {
    int rr = -1;
    if (xcc < 3)
      rr = __hip_atomic_fetch_add(&claims[xcc].cnt, 1, __ATOMIC_RELAXED,
                                  __HIP_MEMORY_SCOPE_WORKGROUP);
    role_sh = (rr >= 0 && rr < 16) ? rr : -1;
  }
  __syncthreads();
  const int rid = role_sh;
  if (rid < 0) return;

  const int L     = (int)xcc;
  const int layer = rid >> 3;
  const int u0    = (rid & 7) * 32;
  const int T     = (L == 0) ? STK : (L == 1) ? BUFF : HIST;
  const int* lenp = (L == 0) ? len_s : (L == 1) ? len_b : len_a;

  const float *W, *bias;
  int K, KP, Kxp;
  if (layer == 0) {
    W = (L == 0) ? sW0 : (L == 1) ? bW0 : aW0;
    bias = (L == 0) ? sb0 : (L == 1) ? bb0 : ab0;
    if (L == 2) { K = 320; KP = 328; Kxp = 64; } else { K = 384; KP = 392; Kxp = 128; }
  } else {
    W = (L == 0) ? sW1 : (L == 1) ? bW1 : aW1;
    bias = (L == 0) ? sb1 : (L == 1) ? bb1 : ab1;
    K = 512; KP = 520; Kxp = 256;
  }
  bf16*  Wt     = (bf16*)sm;                               // [128][KP]
  bf16*  hstage = (bf16*)(sm + 128 * KP * 2);              // [128][36]
  float* sb     = (float*)(sm + 128 * KP * 2 + 9216);      // [128]
  bf16*  Xa     = (bf16*)(sm + 128 * KP * 2 + 9216 + 512); // [128][72] (action L0)

  for (int i = tid; i < K * 128; i += 256) {
    int kk = i >> 7, cc = i & 127;
    int col = (cc >> 5) * 256 + u0 + (cc & 31);
    bf16 v;
    if (layer == 0 && L == 2) {
      if (kk < 64) v = (kk < 50) ? (bf16)W[kk * 1024 + col] : (bf16)0.f;
      else         v = (bf16)W[(kk - 14) * 1024 + col];
    } else v = (bf16)W[kk * 1024 + col];
    Wt[cc * KP + kk] = v;
  }
  if (tid < 128) { int col = (tid >> 5) * 256 + u0 + (tid & 31); sb[tid] = bias[col]; }

  const int wv = tid >> 6, lane = tid & 63, l15 = lane & 15, quad = lane >> 4;
  int lenr[8];
#pragma unroll
  for (int mt = 0; mt < 2; ++mt)
#pragma unroll
    for (int rr = 0; rr < 4; ++rr)
      lenr[mt * 4 + rr] = lenp[32 * wv + 16 * mt + quad * 4 + rr];

  float cst[16], hst[16];
#pragma unroll
  for (int i = 0; i < 16; ++i) { cst[i] = 0.f; hst[i] = 0.f; }

  Ctr* bar = bars + L;
  bf16* h0w = h0buf + L * 2 * 32768;  // [2][128][256]
  bf16* h1w = h1buf + L * 2 * 32768;
  const bf16* xsrc = (L == 0) ? stack_emb : buff_emb;
  const int Tx = (L == 0) ? STK : BUFF;

  __syncthreads();

  for (int p = 0; p <= T; ++p) {
    const bool active = (layer == 0) ? (p < T) : (p >= 1);
    const int  t = (layer == 0) ? p : (p - 1);

    // drop stale L1 lines; this phase's h reads then hit the XCD L2 fresh
    inv_l1();

    if (L == 2 && layer == 0 && active) {  // stage action x_t (50 -> 64 padded)
      for (int i = tid; i < 128 * 32; i += 256) {
        int row = i >> 5, e0 = 2 * (i & 31);
        unsigned v = 0u;
        if (e0 < 50) { int id = hist_id[row * 96 + t]; v = pack2(hist_tab + id * 50 + e0); }
        *(unsigned*)(Xa + row * 72 + e0) = v;
      }
    }
    __syncthreads();

    if (active) {
      f32x4 acc[2][8];
#pragma unroll
      for (int a1 = 0; a1 < 2; ++a1)
#pragma unroll
        for (int a2 = 0; a2 < 8; ++a2) acc[a1][a2] = (f32x4){0.f, 0.f, 0.f, 0.f};

      const bf16* h0r = h0w + ((p - 1) & 1) * 32768;
      const bf16* h1r = h1w + (p & 1) * 32768;

      for (int ks = 0; ks < K / 32; ++ks) {
        int k0 = ks * 32;
        int kq = k0 + quad * 8;
        bf16x8 a[2];
#pragma unroll
        for (int mt = 0; mt < 2; ++mt) {
          int row = 32 * wv + 16 * mt + l15;
          if (layer == 0) {
            if (k0 < Kxp) {
              if (L == 2) a[mt] = *(const bf16x8*)(Xa + row * 72 + kq);
              else        a[mt] = *(const bf16x8*)(xsrc + (row * Tx + t) * 128 + kq);
            } else a[mt] = *(const bf16x8*)(h0r + row * 256 + (kq - Kxp));
          } else {
            if (k0 < 256) a[mt] = *(const bf16x8*)(h0r + row * 256 + kq);
            else          a[mt] = *(const bf16x8*)(h1r + row * 256 + (kq - 256));
          }
        }
#pragma unroll
        for (int nt = 0; nt < 8; ++nt) {
          bf16x8 b = *(const bf16x8*)(Wt + (nt * 16 + l15) * KP + kq);
          acc[0][nt] = __builtin_amdgcn_mfma_f32_16x16x32_bf16(a[0], b, acc[0][nt], 0, 0, 0);
          acc[1][nt] = __builtin_amdgcn_mfma_f32_16x16x32_bf16(a[1], b, acc[1][nt], 0, 0, 0);
        }
      }
      // gates: nt 0,1 = i ; 2,3 = j ; 4,5 = f ; 6,7 = o
#pragma unroll
      for (int mt = 0; mt < 2; ++mt)
#pragma unroll
        for (int g2 = 0; g2 < 2; ++g2)
#pragma unroll
          for (int rr = 0; rr < 4; ++rr) {
            int row = 32 * wv + 16 * mt + quad * 4 + rr;
            float zi = acc[mt][0 + g2][rr] + sb[(0 + g2) * 16 + l15];
            float zj = acc[mt][2 + g2][rr] + sb[(2 + g2) * 16 + l15];
            float zf = acc[mt][4 + g2][rr] + sb[(4 + g2) * 16 + l15];
            float zo = acc[mt][6 + g2][rr] + sb[(6 + g2) * 16 + l15];
            float ig = sigf(zi), jg = tanhf_(zj), fg = sigf(zf + 1.f), og = sigf(zo);
            int idx = mt * 8 + g2 * 4 + rr;
            float cn = cst[idx] * fg + ig * jg;
            float hn = tanhf_(cn) * og;
            bool mk = (t < lenr[mt * 4 + rr]);
            cst[idx] = mk ? cn : cst[idx];
            hst[idx] = mk ? hn : hst[idx];
            hstage[row * 36 + g2 * 16 + l15] = (bf16)hst[idx];
          }
    }
    __syncthreads();
    if (active) {
      bf16* dst = (layer == 0) ? (h0w + (p & 1) * 32768) : (h1w + ((p - 1) & 1) * 32768);
      for (int i = tid; i < 128 * 8; i += 256) {
        int row = i >> 3, c = i & 7;
        unsigned long long v = *(const unsigned long long*)(hstage + row * 36 + c * 4);
        vstore8(dst + row * 256 + u0 + c * 4, v);
      }
    }
    // same-XCD barrier: L2-local atomic + volatile (sc0) poll.
    __syncthreads();  // drains vmcnt -> h stores are in L2 before arrival
    if (tid == 0) {
      __hip_atomic_fetch_add(&bar->cnt, 1, __ATOMIC_RELAXED, __HIP_MEMORY_SCOPE_WORKGROUP);
      const int target = 16 * (p + 1);
      while (*(volatile int*)&bar->cnt < target) { }
    }
    __syncthreads();
  }

  // final h1 -> compact h1out (layer-1 blocks own their 32 cols x all rows)
  if (layer == 1) {
#pragma unroll
    for (int mt = 0; mt < 2; ++mt)
#pragma unroll
      for (int g2 = 0; g2 < 2; ++g2)
#pragma unroll
        for (int rr = 0; rr < 4; ++rr) {
          int row = 32 * wv + 16 * mt + quad * 4 + rr;
          h1out[L * 32768 + row * 256 + u0 + g2 * 16 + l15] = (bf16)hst[mt * 8 + g2 * 4 + rr];
        }
  }
}

// =====================================================================
// Kernel 4: out = concat(h_s,h_b,h_a) @ fW + fb
// =====================================================================
__global__ __launch_bounds__(128) void k_final(
    const bf16* h1out, const float* fW, const float* fb, float* out)
{
  __shared__ float hs[768];
  const int b = blockIdx.x, tid = threadIdx.x;
  for (int i = tid; i < 768; i += 128) {
    int Li = i >> 8, u = i & 255;
    hs[i] = (float)h1out[Li * 32768 + b * 256 + u];
  }
  __syncthreads();
  if (tid < NOUT) {
    float acc = fb[tid];
    for (int u = 0; u < 768; ++u) acc += hs[u] * fW[u * NOUT + tid];
    out[b * NOUT + tid] = acc;
  }
}

// =====================================================================
extern "C" void kernel_launch(void* const* d_in, const int* in_sizes, int n_in,
                              void* d_out, int out_size, void* d_ws, size_t ws_size,
                              hipStream_t stream)
{
  (void)in_sizes; (void)n_in; (void)out_size; (void)ws_size;
  char* ws = (char*)d_ws;
  bf16* h0buf     = (bf16*)(ws + 512);                     // 393216 B
  bf16* h1buf     = (bf16*)(ws + 512 + 393216);            // 393216 B (ends 786944)
  // control + h1out live in comp_emb's head (dead after k_compose):
  Ctr*  claims    = (Ctr*)(ws + 786944);                   // 3 x 256 B
  Ctr*  bars      = (Ctr*)(ws + 786944 + 1024);            // 3 x 256 B
  bf16* h1out     = (bf16*)(ws + 786944 + 4096);           // 196608 B
  bf16* comp_emb  = (bf16*)(ws + 786944);                  // 25165824 B
  bf16* buff_emb  = (bf16*)(ws + 786944 + 25165824);       // 2097152 B
  bf16* stack_emb = (bf16*)(ws + 786944 + 25165824 + 2097152); // 1572864 B

  hipMemsetAsync(ws, 0, 786944, stream);  // h0/h1 initial state

  k_emb<<<1664, 256, 0, stream>>>(
      (const int*)d_in[0], (const int*)d_in[1], (const int*)d_in[2], (const int*)d_in[3],
      (const float*)d_in[13], (const float*)d_in[10], (const float*)d_in[14], (const float*)d_in[15],
      comp_emb, buff_emb);

  k_compose<<<384, 256, 0, stream>>>(
      (const int*)d_in[2], (const int*)d_in[4], (const int*)d_in[5],
      comp_emb, (const float*)d_in[11], (const float*)d_in[16], (const float*)d_in[17],
      stack_emb);

  // comp_emb is dead now -> zero the claim/barrier control block
  hipMemsetAsync(ws + 786944, 0, 4096, stream);

  k_lstm3<<<512, 256, 0, stream>>>(
      (const float*)d_in[18], (const float*)d_in[19], (const float*)d_in[20], (const float*)d_in[21],
      (const float*)d_in[22], (const float*)d_in[23], (const float*)d_in[24], (const float*)d_in[25],
      (const float*)d_in[26], (const float*)d_in[27], (const float*)d_in[28], (const float*)d_in[29],
      stack_emb, buff_emb, (const float*)d_in[12], (const int*)d_in[6],
      (const int*)d_in[7], (const int*)d_in[8], (const int*)d_in[9],
      h0buf, h1buf, h1out, claims, bars);

  k_final<<<128, 128, 0, stream>>>(h1out, (const float*)d_in[30], (const float*)d_in[31],
                                   (float*)d_out);
}